// Round 11
// baseline (1279.802 us; speedup 1.0000x reference)
//
#include <hip/hip_runtime.h>
#include <math.h>

// KDC Lindblad propagator — real-basis reduction + fp64 MFMA + fused-LDS Horner.
// f64 16x16x4 C/D layout (HW-probed round 4): col=lane&15, row=(lane>>4)+4*reg.
//
// Round 11:
//  (a) dgemm reverted VERBATIM to round-9 (48.6 us measured; round-10 k-split
//      doubled FETCH -> memory-bound 107 us. Do not touch without new theory).
//  (b) Horner phase fused into ONE kernel: T acts only on the row index, so
//      columns are independent. Block owns a 2-column LDS strip, runs identity
//      + all 16 sparse T-applies locally (no global reads, no grid sync),
//      writes its W strip once. Replaces 16 launches (~250 us) with one.
// Pipeline: W = Taylor16(tau*T/8) [1 launch]; U = W^8 (3 sq); V = U^32 (5 sq);
// UT+init [1]; 31 chain steps; pops.

#define DS 1024
#define MATD ((size_t)DS * DS * sizeof(double))
#define PA 66

typedef double v4d __attribute__((ext_vector_type(4)));

__device__ inline double Qel(int i, int j) {
    if (i == j + 1) return sqrt((double)i) * 0.70710678118654752440;
    if (j == i + 1) return sqrt((double)j) * 0.70710678118654752440;
    return 0.0;
}

__device__ inline void fill_H(double* Hs, int tid) {
    const double CM2EV = 0.00012398419;
    const double E_S1 = 3.995, E_S2 = 4.9183;
    const double om6a = 596.0 * CM2EV, om10a = 919.0 * CM2EV;
    const double kapA = -0.0964, kapB = 0.1193, lam = 0.1825, gam = -0.018;
    for (int h = tid; h < 1024; h += 256) {
        int r = h >> 5, c = h & 31;
        int e = r >> 4, v6 = (r >> 2) & 3, v10 = r & 3;
        int e2 = c >> 4, w6 = (c >> 2) & 3, w10 = c & 3;
        double val = 0.0;
        if (r == c) val += (e ? E_S2 : E_S1) + om6a * v6 + om10a * v10;
        if (e == e2 && v10 == w10) val += (e ? kapB : kapA) * Qel(v6, w6);
        if (e != e2 && v6 == w6) {
            double q2 = 0.0;
            #pragma unroll
            for (int m = 0; m < 4; ++m) q2 += Qel(v10, m) * Qel(m, w10);
            val += lam * Qel(v10, w10) + gam * q2;
        }
        Hs[h] = val;
    }
}

// --------------------------------------------------------- fused Horner -----
// Block b owns columns {2b, 2b+1} of G (strip in LDS, stride 3 for banks).
// G = I; 16x: G <- I + (tau/8/k) T G; write W strip. Coefficient maps are the
// round-7-validated apply_T logic verbatim.
__global__ __launch_bounds__(256)
void horner_cols(const float* __restrict__ logg, double* __restrict__ W)
{
    __shared__ double Hs[1024];
    __shared__ double bufA[1024 * 3];
    __shared__ double bufB[1024 * 3];
    const int tid = threadIdx.x;
    fill_H(Hs, tid);
    const double g = exp((double)logg[0]);
    const double tau8 = (1.0 / 0.6582119569) / 8.0;
    const int c0 = blockIdx.x * 2;

    for (int q = tid; q < 1024; q += 256) {
        bufA[q * 3 + 0] = (q == c0)     ? 1.0 : 0.0;
        bufA[q * 3 + 1] = (q == c0 + 1) ? 1.0 : 0.0;
    }
    __syncthreads();

    double* cur = bufA;
    double* nxt = bufB;

    for (int k = 16; k >= 1; --k) {
        const double sck = tau8 / (double)k;
        #pragma unroll
        for (int r = 0; r < 4; ++r) {
            const int p = tid + 256 * r;
            const int i = p >> 5, j = p & 31;
            double a0 = 0.0, a1 = 0.0;

#define ADDROW(q, wgt) { double w_ = (wgt); const double* r_ = cur + (q) * 3; \
    a0 += w_ * r_[0]; a1 += w_ * r_[1]; }

            if (i <= j) {   // R-output row
                for (int m = 0; m < 32; ++m) {
                    double c = Hs[i * 32 + m];
                    if (c != 0.0 && m != j) {
                        if (m > j) ADDROW(m * 32 + j, -c)
                        else       ADDROW(j * 32 + m,  c)
                    }
                }
                for (int m = 0; m < 32; ++m) {
                    double c = Hs[m * 32 + j];
                    if (c != 0.0 && m != i) {
                        if (i > m) ADDROW(i * 32 + m,  c)
                        else       ADDROW(m * 32 + i, -c)
                    }
                }
                if (i < 16 && j < 16) ADDROW((i + 16) * 32 + (j + 16), g)
                if (i >= 16 || j >= 16)
                    ADDROW(p, -0.5 * g * (double)((i >= 16) + (j >= 16)))
            } else {        // A-output row
                for (int m = 0; m < 32; ++m) {
                    double c = Hs[i * 32 + m];
                    if (c != 0.0) {
                        int lo = m < j ? m : j, hi = m < j ? j : m;
                        ADDROW(lo * 32 + hi, c)
                    }
                }
                for (int m = 0; m < 32; ++m) {
                    double c = Hs[m * 32 + j];
                    if (c != 0.0) {
                        int lo = m < i ? m : i, hi = m < i ? i : m;
                        ADDROW(lo * 32 + hi, -c)
                    }
                }
                if (i < 16 && j < 16) ADDROW((i + 16) * 32 + (j + 16), g)
                ADDROW(p, -0.5 * g * (double)((i >= 16) + (j >= 16)))
            }
#undef ADDROW

            nxt[p * 3 + 0] = sck * a0 + ((p == c0)     ? 1.0 : 0.0);
            nxt[p * 3 + 1] = sck * a1 + ((p == c0 + 1) ? 1.0 : 0.0);
        }
        __syncthreads();
        double* t = cur; cur = nxt; nxt = t;
    }

    for (int q = tid; q < 1024; q += 256) {
        W[(size_t)q * DS + c0]     = cur[q * 3 + 0];
        W[(size_t)q * DS + c0 + 1] = cur[q * 3 + 1];
    }
}

// --------------------------------------------------------- dgemm (MFMA f64) -
// ROUND-9 VERBATIM. D = A*B. 64x64 tile, 1024 threads (16 waves):
// 4 output quadrants x 4 k-groups (k-split-4 within KT=64); 3-phase reduction.
__global__ __launch_bounds__(1024, 1)
void dgemm(const double* __restrict__ A, const double* __restrict__ B,
           double* __restrict__ D)
{
    __shared__ double As[64 * PA];   // [row][k]
    __shared__ double Bs[64 * PA];   // [k][col]
    const int tid = threadIdx.x;
    const int bm = blockIdx.x << 6, bn = blockIdx.y << 6;
    const int w = tid >> 6, lane = tid & 63;
    const int lr = lane & 15, lk = lane >> 4;
    const int p = w & 3, kg = w >> 2;
    const int wr = (p >> 1) << 5, wc = (p & 1) << 5;

    v4d acc[2][2];
    #pragma unroll
    for (int si = 0; si < 2; ++si)
        #pragma unroll
        for (int sj = 0; sj < 2; ++sj) acc[si][sj] = (v4d){0., 0., 0., 0.};

    const int ra = tid >> 4;          // 0..63
    const int cs = (tid & 15) << 2;   // 0..60
    const double* gA = A + (size_t)(bm + ra) * DS + cs;
    const double* gB = B + (size_t)ra * DS + bn + cs;
    double va[4], vb[4];
    #pragma unroll
    for (int u = 0; u < 4; ++u) { va[u] = gA[u]; vb[u] = gB[u]; }

    for (int kt = 0; kt < DS; kt += 64) {
        #pragma unroll
        for (int u = 0; u < 4; ++u) {
            As[ra * PA + cs + u] = va[u];
            Bs[ra * PA + cs + u] = vb[u];
        }
        __syncthreads();
        if (kt + 64 < DS) {
            #pragma unroll
            for (int u = 0; u < 4; ++u) {
                va[u] = gA[kt + 64 + u];
                vb[u] = gB[(size_t)(kt + 64) * DS + u];
            }
        }
        #pragma unroll
        for (int s = 0; s < 4; ++s) {
            int k = (kg << 4) + (s << 2) + lk;
            double a0 = As[(wr + lr) * PA + k];
            double a1 = As[(wr + 16 + lr) * PA + k];
            double b0 = Bs[k * PA + wc + lr];
            double b1 = Bs[k * PA + wc + 16 + lr];
            acc[0][0] = __builtin_amdgcn_mfma_f64_16x16x4f64(a0, b0, acc[0][0], 0, 0, 0);
            acc[0][1] = __builtin_amdgcn_mfma_f64_16x16x4f64(a0, b1, acc[0][1], 0, 0, 0);
            acc[1][0] = __builtin_amdgcn_mfma_f64_16x16x4f64(a1, b0, acc[1][0], 0, 0, 0);
            acc[1][1] = __builtin_amdgcn_mfma_f64_16x16x4f64(a1, b1, acc[1][1], 0, 0, 0);
        }
        __syncthreads();
    }

    double* red = As;   // 64x64
    if (kg == 3) {
        #pragma unroll
        for (int si = 0; si < 2; ++si)
            #pragma unroll
            for (int sj = 0; sj < 2; ++sj)
                #pragma unroll
                for (int r = 0; r < 4; ++r)
                    red[(wr + si * 16 + lk + 4 * r) * 64 + wc + sj * 16 + lr]
                        = acc[si][sj][r];
    }
    __syncthreads();
    if (kg == 2) {
        #pragma unroll
        for (int si = 0; si < 2; ++si)
            #pragma unroll
            for (int sj = 0; sj < 2; ++sj)
                #pragma unroll
                for (int r = 0; r < 4; ++r)
                    red[(wr + si * 16 + lk + 4 * r) * 64 + wc + sj * 16 + lr]
                        += acc[si][sj][r];
    }
    __syncthreads();
    if (kg == 1) {
        #pragma unroll
        for (int si = 0; si < 2; ++si)
            #pragma unroll
            for (int sj = 0; sj < 2; ++sj)
                #pragma unroll
                for (int r = 0; r < 4; ++r)
                    red[(wr + si * 16 + lk + 4 * r) * 64 + wc + sj * 16 + lr]
                        += acc[si][sj][r];
    }
    __syncthreads();
    if (kg == 0) {
        #pragma unroll
        for (int si = 0; si < 2; ++si)
            #pragma unroll
            for (int sj = 0; sj < 2; ++sj) {
                int col = bn + wc + sj * 16 + lr;
                #pragma unroll
                for (int r = 0; r < 4; ++r) {
                    int row = bm + wr + si * 16 + lk + 4 * r;
                    D[(size_t)row * DS + col] = acc[si][sj][r]
                        + red[(wr + si * 16 + lk + 4 * r) * 64 + wc + sj * 16 + lr];
                }
            }
    }
}

// --------------------------------------------------------- transpose + init -
__global__ __launch_bounds__(256)
void transposeK(const double* __restrict__ M, double* __restrict__ MT,
                double* __restrict__ Y, double* __restrict__ Z)
{
    __shared__ double t[32][33];
    int bx = blockIdx.x << 5, by = blockIdx.y << 5;
    int x = threadIdx.x & 31, y = threadIdx.x >> 5;
    #pragma unroll
    for (int dy = 0; dy < 32; dy += 8)
        t[y + dy][x] = M[(size_t)(by + y + dy) * DS + bx + x];
    __syncthreads();
    #pragma unroll
    for (int dy = 0; dy < 32; dy += 8)
        MT[(size_t)(bx + y + dy) * DS + by + x] = t[x][y + dy];

    int fb = (blockIdx.y << 5) | blockIdx.x;
    if (fb < 12) {
        int idx = fb * 256 + threadIdx.x;
        if (idx < 2048) {
            int k = idx >> 10, i = idx & 1023;
            double v = 0.0;
            if (i % 33 == 0) {
                int a = i / 33;
                if ((a < 16) == (k == 0)) v = 1.0;
            }
            Y[idx] = v;
        } else if (idx < 3072) {
            Z[idx - 2048] = (idx == 2048 + 528) ? 1.0 : 0.0;
        }
    }
}

// --------------------------------------------------------- chains -----------
__global__ __launch_bounds__(256)
void chain_step(const double* __restrict__ UT, const double* __restrict__ V,
                const double* __restrict__ Yin, double* __restrict__ Yout,
                const double* __restrict__ Zin, double* __restrict__ Zout)
{
    int gw = blockIdx.x * 4 + (threadIdx.x >> 6);
    int lane = threadIdx.x & 63;
    if (gw < 1024) {
        const double* row = UT + (size_t)gw * DS;
        double s0 = 0.0, s1 = 0.0;
        for (int kk = lane; kk < DS; kk += 64) {
            double m = row[kk];
            s0 += m * Yin[kk];
            s1 += m * Yin[DS + kk];
        }
        #pragma unroll
        for (int off = 32; off; off >>= 1) {
            s0 += __shfl_down(s0, off);
            s1 += __shfl_down(s1, off);
        }
        if (lane == 0) { Yout[gw] = s0; Yout[DS + gw] = s1; }
    } else {
        int r = gw - 1024;
        const double* row = V + (size_t)r * DS;
        double s = 0.0;
        for (int kk = lane; kk < DS; kk += 64) s += row[kk] * Zin[kk];
        #pragma unroll
        for (int off = 32; off; off >>= 1) s += __shfl_down(s, off);
        if (lane == 0) Zout[r] = s;
    }
}

// --------------------------------------------------------- output -----------
__global__ __launch_bounds__(128)
void final_pops(const double* __restrict__ Y, const double* __restrict__ Z,
                float* __restrict__ out, int n)
{
    int t = blockIdx.x;
    int k = threadIdx.x >> 6, lane = threadIdx.x & 63;
    int a = t & 31, j = t >> 5;
    const double* y = Y + (size_t)a * 2048 + (size_t)k * 1024;
    const double* z = Z + (size_t)j * 1024;
    double s = 0.0;
    for (int i = lane; i < 1024; i += 64) s += y[i] * z[i];
    #pragma unroll
    for (int off = 32; off; off >>= 1) s += __shfl_down(s, off);
    if (lane == 0) {
        out[(size_t)(k + 1) * n + t] = (float)s;
        if (k == 0) out[t] = 0.0f;
    }
}

// --------------------------------------------------------- host -------------
extern "C" void kernel_launch(void* const* d_in, const int* in_sizes, int n_in,
                              void* d_out, int out_size, void* d_ws, size_t ws_size,
                              hipStream_t stream)
{
    const float* logg = (const float*)d_in[0];
    float* out = (float*)d_out;
    const int n = out_size / 3;
    (void)in_sizes; (void)n_in; (void)ws_size;

    char* ws = (char*)d_ws;
    double* b0 = (double*)(ws + 0 * MATD);
    double* b1 = (double*)(ws + 1 * MATD);
    double* b2 = (double*)(ws + 2 * MATD);
    double* b3 = (double*)(ws + 3 * MATD);
    double* Y  = (double*)(ws + 4 * MATD);   // 32 x 2 x 1024
    double* Z  = Y + 32 * 2048;              // 32 x 1024

    dim3 g2(16, 16);

    // ---- W = Taylor16(tau*T/8), one fused launch -> b0 ----
    horner_cols<<<512, 256, 0, stream>>>(logg, b0);

    // ---- U = W^8 (3 sq), V = U^32 (5 sq) ----
    dgemm<<<g2, 1024, 0, stream>>>(b0, b0, b1);   // W^2
    dgemm<<<g2, 1024, 0, stream>>>(b1, b1, b2);   // W^4
    dgemm<<<g2, 1024, 0, stream>>>(b2, b2, b3);   // U = W^8
    dgemm<<<g2, 1024, 0, stream>>>(b3, b3, b1);   // U^2
    dgemm<<<g2, 1024, 0, stream>>>(b1, b1, b2);   // U^4
    dgemm<<<g2, 1024, 0, stream>>>(b2, b2, b1);   // U^8
    dgemm<<<g2, 1024, 0, stream>>>(b1, b1, b2);   // U^16
    dgemm<<<g2, 1024, 0, stream>>>(b2, b2, b1);   // V = U^32

    // ---- chains: UT in b0, Y/Z init merged into transpose ----
    transposeK<<<dim3(32, 32), 256, 0, stream>>>(b3, b0, Y, Z);
    for (int a = 1; a < 32; ++a)
        chain_step<<<512, 256, 0, stream>>>(b0, b1,
            Y + (size_t)(a - 1) * 2048, Y + (size_t)a * 2048,
            Z + (size_t)(a - 1) * 1024, Z + (size_t)a * 1024);
    final_pops<<<n, 128, 0, stream>>>(Y, Z, out, n);
}

// Round 12
// 1269.139 us; speedup vs baseline: 1.0084x; 1.0084x over previous
//
#include <hip/hip_runtime.h>
#include <math.h>

// KDC Lindblad propagator — real-basis reduction + fp64 MFMA + sparse Horner.
// f64 16x16x4 C/D layout (HW-probed round 4): col=lane&15, row=(lane>>4)+4*reg.
//
// Round 12 = round-9 Horner + dgemm (verbatim, measured) with the chain phase
// restructured: t = a + 64j. Y_a (a=0..63, 2 trace rows each) built by
// DOUBLING with the squaring chain's own intermediates (U^1..U^32 — no extra
// GEMMs, no transpose): Y[M..2M) = Y[0..M) @ U^{2^s}. Z_j = (U^64)^j x0 via
// 15 light matvecs (U^64 = 1 extra dgemm). Replaces 31 fused chain steps.
// horner_cols (round 11) reverted: per-thread (i,j) broke branch uniformity
// (5.2e7 LDS conflicts, 669 us) — apply_T's block-uniform gather is the
// right structure.

#define DS 1024
#define MATD ((size_t)DS * DS * sizeof(double))
#define PA 66

typedef double v4d __attribute__((ext_vector_type(4)));

__device__ inline double Qel(int i, int j) {
    if (i == j + 1) return sqrt((double)i) * 0.70710678118654752440;
    if (j == i + 1) return sqrt((double)j) * 0.70710678118654752440;
    return 0.0;
}

__device__ inline void fill_H(double* Hs, int tid) {
    const double CM2EV = 0.00012398419;
    const double E_S1 = 3.995, E_S2 = 4.9183;
    const double om6a = 596.0 * CM2EV, om10a = 919.0 * CM2EV;
    const double kapA = -0.0964, kapB = 0.1193, lam = 0.1825, gam = -0.018;
    for (int h = tid; h < 1024; h += 256) {
        int r = h >> 5, c = h & 31;
        int e = r >> 4, v6 = (r >> 2) & 3, v10 = r & 3;
        int e2 = c >> 4, w6 = (c >> 2) & 3, w10 = c & 3;
        double val = 0.0;
        if (r == c) val += (e ? E_S2 : E_S1) + om6a * v6 + om10a * v10;
        if (e == e2 && v10 == w10) val += (e ? kapB : kapA) * Qel(v6, w6);
        if (e != e2 && v6 == w6) {
            double q2 = 0.0;
            #pragma unroll
            for (int m = 0; m < 4; ++m) q2 += Qel(v10, m) * Qel(m, w10);
            val += lam * Qel(v10, w10) + gam * q2;
        }
        Hs[h] = val;
    }
}

// --------------------------------------------------------- build G16 --------
__global__ __launch_bounds__(256)
void build_G16(const float* __restrict__ logg, double* __restrict__ X)
{
    __shared__ double Hs[1024];
    int tid = threadIdx.x;
    fill_H(Hs, tid);
    __syncthreads();
    double g = exp((double)logg[0]);
    const double sc = ((1.0 / 0.6582119569) / 8.0) / 16.0;
    int idx = blockIdx.x * 256 + tid;
    int r = idx >> 10, c = idx & 1023;
    int i = r >> 5, j = r & 31;
    int k = c >> 5, l = c & 31;
    double t = 0.0;
    if (k <= l) {
        if (i <= j) {
            if (i < 16 && j < 16) {
                int p = i + 16, q = j + 16;
                if ((p == k && q == l) || (p == l && q == k)) t += g;
            }
            if (i == k && j == l) t -= 0.5 * g * ((i >= 16) + (j >= 16));
        } else {
            if (j == l) t += Hs[i * 32 + k];
            if (k != l && j == k) t += Hs[i * 32 + l];
            if (i == k) t -= Hs[l * 32 + j];
            if (k != l && i == l) t -= Hs[k * 32 + j];
        }
    } else {
        if (i <= j) {
            double ha = 0.0;
            if (j == l) ha += Hs[i * 32 + k];
            if (j == k) ha -= Hs[i * 32 + l];
            if (i == k) ha -= Hs[l * 32 + j];
            if (i == l) ha += Hs[k * 32 + j];
            t -= ha;
        } else {
            if (i < 16 && j < 16 && (i + 16 == k) && (j + 16 == l)) t += g;
            if (i == k && j == l) t -= 0.5 * g * ((i >= 16) + (j >= 16));
        }
    }
    X[idx] = t * sc + ((r == c) ? 1.0 : 0.0);
}

// --------------------------------------------------------- sparse T-apply ---
__global__ __launch_bounds__(256)
void apply_T(const float* __restrict__ logg, const double* __restrict__ M,
             double* __restrict__ O, double invk)
{
    __shared__ double Hs[1024];
    const int tid = threadIdx.x;
    fill_H(Hs, tid);
    __syncthreads();
    const double g = exp((double)logg[0]);
    const double sck = ((1.0 / 0.6582119569) / 8.0) * invk;
    const int p = blockIdx.x;
    const int i = p >> 5, j = p & 31;

    double a0 = 0.0, a1 = 0.0, a2 = 0.0, a3 = 0.0;
    const int e = tid;

#define ADDROW(q, wgt) { const double* r_ = M + (size_t)(q) * DS; double w_ = (wgt); \
    a0 += w_ * r_[e]; a1 += w_ * r_[e + 256];                                        \
    a2 += w_ * r_[e + 512]; a3 += w_ * r_[e + 768]; }

    if (i <= j) {
        for (int m = 0; m < 32; ++m) {
            double c = Hs[i * 32 + m];
            if (c != 0.0 && m != j) {
                if (m > j) ADDROW(m * 32 + j, -c)
                else       ADDROW(j * 32 + m,  c)
            }
        }
        for (int m = 0; m < 32; ++m) {
            double c = Hs[m * 32 + j];
            if (c != 0.0 && m != i) {
                if (i > m) ADDROW(i * 32 + m,  c)
                else       ADDROW(m * 32 + i, -c)
            }
        }
        if (i < 16 && j < 16) ADDROW((i + 16) * 32 + (j + 16), g)
        if (i >= 16 || j >= 16)
            ADDROW(p, -0.5 * g * (double)((i >= 16) + (j >= 16)))
    } else {
        for (int m = 0; m < 32; ++m) {
            double c = Hs[i * 32 + m];
            if (c != 0.0) {
                int lo = m < j ? m : j, hi = m < j ? j : m;
                ADDROW(lo * 32 + hi, c)
            }
        }
        for (int m = 0; m < 32; ++m) {
            double c = Hs[m * 32 + j];
            if (c != 0.0) {
                int lo = m < i ? m : i, hi = m < i ? i : m;
                ADDROW(lo * 32 + hi, -c)
            }
        }
        if (i < 16 && j < 16) ADDROW((i + 16) * 32 + (j + 16), g)
        ADDROW(p, -0.5 * g * (double)((i >= 16) + (j >= 16)))
    }
#undef ADDROW

    size_t base = (size_t)p * DS;
    O[base + e]       = sck * a0 + ((p == e)       ? 1.0 : 0.0);
    O[base + e + 256] = sck * a1 + ((p == e + 256) ? 1.0 : 0.0);
    O[base + e + 512] = sck * a2 + ((p == e + 512) ? 1.0 : 0.0);
    O[base + e + 768] = sck * a3 + ((p == e + 768) ? 1.0 : 0.0);
}

// --------------------------------------------------------- dgemm (MFMA f64) -
// ROUND-9 VERBATIM. D = A*B. 64x64 tile, 1024 threads (16 waves).
__global__ __launch_bounds__(1024, 1)
void dgemm(const double* __restrict__ A, const double* __restrict__ B,
           double* __restrict__ D)
{
    __shared__ double As[64 * PA];
    __shared__ double Bs[64 * PA];
    const int tid = threadIdx.x;
    const int bm = blockIdx.x << 6, bn = blockIdx.y << 6;
    const int w = tid >> 6, lane = tid & 63;
    const int lr = lane & 15, lk = lane >> 4;
    const int p = w & 3, kg = w >> 2;
    const int wr = (p >> 1) << 5, wc = (p & 1) << 5;

    v4d acc[2][2];
    #pragma unroll
    for (int si = 0; si < 2; ++si)
        #pragma unroll
        for (int sj = 0; sj < 2; ++sj) acc[si][sj] = (v4d){0., 0., 0., 0.};

    const int ra = tid >> 4;
    const int cs = (tid & 15) << 2;
    const double* gA = A + (size_t)(bm + ra) * DS + cs;
    const double* gB = B + (size_t)ra * DS + bn + cs;
    double va[4], vb[4];
    #pragma unroll
    for (int u = 0; u < 4; ++u) { va[u] = gA[u]; vb[u] = gB[u]; }

    for (int kt = 0; kt < DS; kt += 64) {
        #pragma unroll
        for (int u = 0; u < 4; ++u) {
            As[ra * PA + cs + u] = va[u];
            Bs[ra * PA + cs + u] = vb[u];
        }
        __syncthreads();
        if (kt + 64 < DS) {
            #pragma unroll
            for (int u = 0; u < 4; ++u) {
                va[u] = gA[kt + 64 + u];
                vb[u] = gB[(size_t)(kt + 64) * DS + u];
            }
        }
        #pragma unroll
        for (int s = 0; s < 4; ++s) {
            int k = (kg << 4) + (s << 2) + lk;
            double a0 = As[(wr + lr) * PA + k];
            double a1 = As[(wr + 16 + lr) * PA + k];
            double b0 = Bs[k * PA + wc + lr];
            double b1 = Bs[k * PA + wc + 16 + lr];
            acc[0][0] = __builtin_amdgcn_mfma_f64_16x16x4f64(a0, b0, acc[0][0], 0, 0, 0);
            acc[0][1] = __builtin_amdgcn_mfma_f64_16x16x4f64(a0, b1, acc[0][1], 0, 0, 0);
            acc[1][0] = __builtin_amdgcn_mfma_f64_16x16x4f64(a1, b0, acc[1][0], 0, 0, 0);
            acc[1][1] = __builtin_amdgcn_mfma_f64_16x16x4f64(a1, b1, acc[1][1], 0, 0, 0);
        }
        __syncthreads();
    }

    double* red = As;
    if (kg == 3) {
        #pragma unroll
        for (int si = 0; si < 2; ++si)
            #pragma unroll
            for (int sj = 0; sj < 2; ++sj)
                #pragma unroll
                for (int r = 0; r < 4; ++r)
                    red[(wr + si * 16 + lk + 4 * r) * 64 + wc + sj * 16 + lr]
                        = acc[si][sj][r];
    }
    __syncthreads();
    if (kg == 2) {
        #pragma unroll
        for (int si = 0; si < 2; ++si)
            #pragma unroll
            for (int sj = 0; sj < 2; ++sj)
                #pragma unroll
                for (int r = 0; r < 4; ++r)
                    red[(wr + si * 16 + lk + 4 * r) * 64 + wc + sj * 16 + lr]
                        += acc[si][sj][r];
    }
    __syncthreads();
    if (kg == 1) {
        #pragma unroll
        for (int si = 0; si < 2; ++si)
            #pragma unroll
            for (int sj = 0; sj < 2; ++sj)
                #pragma unroll
                for (int r = 0; r < 4; ++r)
                    red[(wr + si * 16 + lk + 4 * r) * 64 + wc + sj * 16 + lr]
                        += acc[si][sj][r];
    }
    __syncthreads();
    if (kg == 0) {
        #pragma unroll
        for (int si = 0; si < 2; ++si)
            #pragma unroll
            for (int sj = 0; sj < 2; ++sj) {
                int col = bn + wc + sj * 16 + lr;
                #pragma unroll
                for (int r = 0; r < 4; ++r) {
                    int row = bm + wr + si * 16 + lk + 4 * r;
                    D[(size_t)row * DS + col] = acc[si][sj][r]
                        + red[(wr + si * 16 + lk + 4 * r) * 64 + wc + sj * 16 + lr];
                }
            }
    }
}

// --------------------------------------------------------- init Y/Z ---------
// Y: 128 rows (r = 2a+k). Rows 0,1 = trace rows of P1,P2; rest zero
// (zero rows double harmlessly: 0 @ P = 0, atomicAdd(0)).
__global__ __launch_bounds__(256)
void init_YZ(double* __restrict__ Y, double* __restrict__ Z)
{
    int idx = blockIdx.x * 256 + threadIdx.x;
    if (idx < 128 * 1024) {
        int r = idx >> 10, i = idx & 1023;
        double v = 0.0;
        if (r < 2 && i % 33 == 0) {
            int a = i / 33;
            if ((a < 16) == (r == 0)) v = 1.0;
        }
        Y[idx] = v;
    } else if (idx < 128 * 1024 + 1024) {
        int i = idx - 128 * 1024;
        Z[i] = (i == 528) ? 1.0 : 0.0;
    }
}

// --------------------------------------------------------- Y-doubling -------
// Y[M + r] += Y[r] @ P  for r in [0, 32*gridDim.z). Rows >= M of the input
// are zero, so their contributions are zero (rows [M..2M) get exactly
// Y[0..M) @ P). k-chunked grid (16 cols x 8 kchunks x rb); 4-wave LDS
// reduce then fp64 atomicAdd into the (zeroed) output rows.
__global__ __launch_bounds__(256)
void ydouble(const double* __restrict__ P, double* __restrict__ Y, int M)
{
    __shared__ double red[32 * 64];
    const int tid = threadIdx.x;
    const int col = tid & 63, kg = tid >> 6;
    const int c = (blockIdx.x << 6) + col;
    const int kb = (blockIdx.y << 7) + (kg << 5);
    const int rb = blockIdx.z << 5;

    double acc[32];
    #pragma unroll
    for (int r = 0; r < 32; ++r) acc[r] = 0.0;

    for (int kk = 0; kk < 32; ++kk) {
        int k = kb + kk;
        double pv = P[(size_t)k * DS + c];
        #pragma unroll
        for (int r = 0; r < 32; ++r)
            acc[r] += Y[(size_t)(rb + r) * DS + k] * pv;   // wave-uniform load
    }

    if (kg == 3) {
        #pragma unroll
        for (int r = 0; r < 32; ++r) red[r * 64 + col] = acc[r];
    }
    __syncthreads();
    if (kg == 2) {
        #pragma unroll
        for (int r = 0; r < 32; ++r) red[r * 64 + col] += acc[r];
    }
    __syncthreads();
    if (kg == 1) {
        #pragma unroll
        for (int r = 0; r < 32; ++r) red[r * 64 + col] += acc[r];
    }
    __syncthreads();
    if (kg == 0) {
        #pragma unroll
        for (int r = 0; r < 32; ++r) red[r * 64 + col] += acc[r];
    }
    __syncthreads();
    for (int idx = tid; idx < 2048; idx += 256) {
        int r = idx >> 6, cc = idx & 63;
        atomicAdd(&Y[(size_t)(M + rb + r) * DS + (blockIdx.x << 6) + cc],
                  red[idx]);
    }
}

// --------------------------------------------------------- Z matvec ---------
__global__ __launch_bounds__(256)
void zstep(const double* __restrict__ V, const double* __restrict__ Zin,
           double* __restrict__ Zout)
{
    int row = blockIdx.x * 4 + (threadIdx.x >> 6);
    int lane = threadIdx.x & 63;
    const double* r_ = V + (size_t)row * DS;
    double s = 0.0;
    for (int k = lane; k < DS; k += 64) s += r_[k] * Zin[k];
    #pragma unroll
    for (int off = 32; off; off >>= 1) s += __shfl_down(s, off);
    if (lane == 0) Zout[row] = s;
}

// --------------------------------------------------------- output -----------
// t = a + 64 j; y = Y row (2a+k); z = Z[j].
__global__ __launch_bounds__(128)
void final_pops(const double* __restrict__ Y, const double* __restrict__ Z,
                float* __restrict__ out, int n)
{
    int t = blockIdx.x;
    int k = threadIdx.x >> 6, lane = threadIdx.x & 63;
    int a = t & 63, j = t >> 6;
    const double* y = Y + (size_t)(2 * a + k) * 1024;
    const double* z = Z + (size_t)j * 1024;
    double s = 0.0;
    for (int i = lane; i < 1024; i += 64) s += y[i] * z[i];
    #pragma unroll
    for (int off = 32; off; off >>= 1) s += __shfl_down(s, off);
    if (lane == 0) {
        out[(size_t)(k + 1) * n + t] = (float)s;
        if (k == 0) out[t] = 0.0f;
    }
}

// --------------------------------------------------------- host -------------
extern "C" void kernel_launch(void* const* d_in, const int* in_sizes, int n_in,
                              void* d_out, int out_size, void* d_ws, size_t ws_size,
                              hipStream_t stream)
{
    const float* logg = (const float*)d_in[0];
    float* out = (float*)d_out;
    const int n = out_size / 3;
    (void)in_sizes; (void)n_in; (void)ws_size;

    char* ws = (char*)d_ws;
    double* b0 = (double*)(ws + 0 * MATD);
    double* b1 = (double*)(ws + 1 * MATD);
    double* b2 = (double*)(ws + 2 * MATD);
    double* Y  = (double*)(ws + 3 * MATD);   // 128 rows x 1024
    double* Z  = Y + 128 * 1024;             // 16 x 1024

    dim3 g2(16, 16);

    // ---- W = Taylor16(tau*T/8): G16 dense, then 15 sparse applies ----
    build_G16<<<4096, 256, 0, stream>>>(logg, b0);
    double* src = b0; double* dst = b1;
    for (int k = 15; k >= 1; --k) {
        apply_T<<<1024, 256, 0, stream>>>(logg, src, dst, 1.0 / (double)k);
        double* t = src; src = dst; dst = t;
    }
    // W in b1

    init_YZ<<<516, 256, 0, stream>>>(Y, Z);

    // ---- squarings interleaved with Y-doubling ----
    dgemm<<<g2, 1024, 0, stream>>>(b1, b1, b0);   // W^2
    dgemm<<<g2, 1024, 0, stream>>>(b0, b0, b2);   // W^4
    dgemm<<<g2, 1024, 0, stream>>>(b2, b2, b0);   // U = W^8
    ydouble<<<dim3(16, 8, 1), 256, 0, stream>>>(b0, Y, 2);    // a +=1  (U)
    dgemm<<<g2, 1024, 0, stream>>>(b0, b0, b1);   // U^2
    ydouble<<<dim3(16, 8, 1), 256, 0, stream>>>(b1, Y, 4);    // a +=2
    dgemm<<<g2, 1024, 0, stream>>>(b1, b1, b2);   // U^4
    ydouble<<<dim3(16, 8, 1), 256, 0, stream>>>(b2, Y, 8);    // a +=4
    dgemm<<<g2, 1024, 0, stream>>>(b2, b2, b1);   // U^8
    ydouble<<<dim3(16, 8, 1), 256, 0, stream>>>(b1, Y, 16);   // a +=8
    dgemm<<<g2, 1024, 0, stream>>>(b1, b1, b2);   // U^16
    ydouble<<<dim3(16, 8, 1), 256, 0, stream>>>(b2, Y, 32);   // a +=16
    dgemm<<<g2, 1024, 0, stream>>>(b2, b2, b1);   // U^32
    ydouble<<<dim3(16, 8, 2), 256, 0, stream>>>(b1, Y, 64);   // a +=32
    dgemm<<<g2, 1024, 0, stream>>>(b1, b1, b2);   // U^64

    // ---- Z chain: z_j = (U^64)^j x0, j = 1..15 ----
    for (int j = 1; j < 16; ++j)
        zstep<<<256, 256, 0, stream>>>(b2, Z + (size_t)(j - 1) * 1024,
                                       Z + (size_t)j * 1024);

    final_pops<<<n, 128, 0, stream>>>(Y, Z, out, n);
}

// Round 13
// 848.280 us; speedup vs baseline: 1.5087x; 1.4961x over previous
//
#include <hip/hip_runtime.h>
#include <math.h>

// KDC Lindblad propagator — real-basis reduction + fp64 MFMA + sparse Horner.
// f64 16x16x4 C/D layout (HW-probed round 4): col=lane&15, row=(lane>>4)+4*reg.
//
// Round 13 = round-12 algebra (t = a + 64j, Y-doubling off the squaring
// chain's own intermediates, Z via U^64 — all absmax-0-validated) with
// ydouble reimplemented as two parallel passes (round-12's one-kernel
// version was latency-serial: 128 blocks, wave-uniform loads, 86 us):
//   ypart:   grid (16 col x 16 k x rowgroups): LDS-staged Y rows, per-thread
//            col accumulation, 4-wave LDS reduce, per-kblock partials.
//   yreduce: sum 16 partials into Y rows [M..). Zero-row reads/writes benign.

#define DS 1024
#define MATD ((size_t)DS * DS * sizeof(double))
#define PA 66

typedef double v4d __attribute__((ext_vector_type(4)));

__device__ inline double Qel(int i, int j) {
    if (i == j + 1) return sqrt((double)i) * 0.70710678118654752440;
    if (j == i + 1) return sqrt((double)j) * 0.70710678118654752440;
    return 0.0;
}

__device__ inline void fill_H(double* Hs, int tid) {
    const double CM2EV = 0.00012398419;
    const double E_S1 = 3.995, E_S2 = 4.9183;
    const double om6a = 596.0 * CM2EV, om10a = 919.0 * CM2EV;
    const double kapA = -0.0964, kapB = 0.1193, lam = 0.1825, gam = -0.018;
    for (int h = tid; h < 1024; h += 256) {
        int r = h >> 5, c = h & 31;
        int e = r >> 4, v6 = (r >> 2) & 3, v10 = r & 3;
        int e2 = c >> 4, w6 = (c >> 2) & 3, w10 = c & 3;
        double val = 0.0;
        if (r == c) val += (e ? E_S2 : E_S1) + om6a * v6 + om10a * v10;
        if (e == e2 && v10 == w10) val += (e ? kapB : kapA) * Qel(v6, w6);
        if (e != e2 && v6 == w6) {
            double q2 = 0.0;
            #pragma unroll
            for (int m = 0; m < 4; ++m) q2 += Qel(v10, m) * Qel(m, w10);
            val += lam * Qel(v10, w10) + gam * q2;
        }
        Hs[h] = val;
    }
}

// --------------------------------------------------------- build G16 --------
__global__ __launch_bounds__(256)
void build_G16(const float* __restrict__ logg, double* __restrict__ X)
{
    __shared__ double Hs[1024];
    int tid = threadIdx.x;
    fill_H(Hs, tid);
    __syncthreads();
    double g = exp((double)logg[0]);
    const double sc = ((1.0 / 0.6582119569) / 8.0) / 16.0;
    int idx = blockIdx.x * 256 + tid;
    int r = idx >> 10, c = idx & 1023;
    int i = r >> 5, j = r & 31;
    int k = c >> 5, l = c & 31;
    double t = 0.0;
    if (k <= l) {
        if (i <= j) {
            if (i < 16 && j < 16) {
                int p = i + 16, q = j + 16;
                if ((p == k && q == l) || (p == l && q == k)) t += g;
            }
            if (i == k && j == l) t -= 0.5 * g * ((i >= 16) + (j >= 16));
        } else {
            if (j == l) t += Hs[i * 32 + k];
            if (k != l && j == k) t += Hs[i * 32 + l];
            if (i == k) t -= Hs[l * 32 + j];
            if (k != l && i == l) t -= Hs[k * 32 + j];
        }
    } else {
        if (i <= j) {
            double ha = 0.0;
            if (j == l) ha += Hs[i * 32 + k];
            if (j == k) ha -= Hs[i * 32 + l];
            if (i == k) ha -= Hs[l * 32 + j];
            if (i == l) ha += Hs[k * 32 + j];
            t -= ha;
        } else {
            if (i < 16 && j < 16 && (i + 16 == k) && (j + 16 == l)) t += g;
            if (i == k && j == l) t -= 0.5 * g * ((i >= 16) + (j >= 16));
        }
    }
    X[idx] = t * sc + ((r == c) ? 1.0 : 0.0);
}

// --------------------------------------------------------- sparse T-apply ---
__global__ __launch_bounds__(256)
void apply_T(const float* __restrict__ logg, const double* __restrict__ M,
             double* __restrict__ O, double invk)
{
    __shared__ double Hs[1024];
    const int tid = threadIdx.x;
    fill_H(Hs, tid);
    __syncthreads();
    const double g = exp((double)logg[0]);
    const double sck = ((1.0 / 0.6582119569) / 8.0) * invk;
    const int p = blockIdx.x;
    const int i = p >> 5, j = p & 31;

    double a0 = 0.0, a1 = 0.0, a2 = 0.0, a3 = 0.0;
    const int e = tid;

#define ADDROW(q, wgt) { const double* r_ = M + (size_t)(q) * DS; double w_ = (wgt); \
    a0 += w_ * r_[e]; a1 += w_ * r_[e + 256];                                        \
    a2 += w_ * r_[e + 512]; a3 += w_ * r_[e + 768]; }

    if (i <= j) {
        for (int m = 0; m < 32; ++m) {
            double c = Hs[i * 32 + m];
            if (c != 0.0 && m != j) {
                if (m > j) ADDROW(m * 32 + j, -c)
                else       ADDROW(j * 32 + m,  c)
            }
        }
        for (int m = 0; m < 32; ++m) {
            double c = Hs[m * 32 + j];
            if (c != 0.0 && m != i) {
                if (i > m) ADDROW(i * 32 + m,  c)
                else       ADDROW(m * 32 + i, -c)
            }
        }
        if (i < 16 && j < 16) ADDROW((i + 16) * 32 + (j + 16), g)
        if (i >= 16 || j >= 16)
            ADDROW(p, -0.5 * g * (double)((i >= 16) + (j >= 16)))
    } else {
        for (int m = 0; m < 32; ++m) {
            double c = Hs[i * 32 + m];
            if (c != 0.0) {
                int lo = m < j ? m : j, hi = m < j ? j : m;
                ADDROW(lo * 32 + hi, c)
            }
        }
        for (int m = 0; m < 32; ++m) {
            double c = Hs[m * 32 + j];
            if (c != 0.0) {
                int lo = m < i ? m : i, hi = m < i ? i : m;
                ADDROW(lo * 32 + hi, -c)
            }
        }
        if (i < 16 && j < 16) ADDROW((i + 16) * 32 + (j + 16), g)
        ADDROW(p, -0.5 * g * (double)((i >= 16) + (j >= 16)))
    }
#undef ADDROW

    size_t base = (size_t)p * DS;
    O[base + e]       = sck * a0 + ((p == e)       ? 1.0 : 0.0);
    O[base + e + 256] = sck * a1 + ((p == e + 256) ? 1.0 : 0.0);
    O[base + e + 512] = sck * a2 + ((p == e + 512) ? 1.0 : 0.0);
    O[base + e + 768] = sck * a3 + ((p == e + 768) ? 1.0 : 0.0);
}

// --------------------------------------------------------- dgemm (MFMA f64) -
// ROUND-9 VERBATIM. D = A*B. 64x64 tile, 1024 threads (16 waves).
__global__ __launch_bounds__(1024, 1)
void dgemm(const double* __restrict__ A, const double* __restrict__ B,
           double* __restrict__ D)
{
    __shared__ double As[64 * PA];
    __shared__ double Bs[64 * PA];
    const int tid = threadIdx.x;
    const int bm = blockIdx.x << 6, bn = blockIdx.y << 6;
    const int w = tid >> 6, lane = tid & 63;
    const int lr = lane & 15, lk = lane >> 4;
    const int p = w & 3, kg = w >> 2;
    const int wr = (p >> 1) << 5, wc = (p & 1) << 5;

    v4d acc[2][2];
    #pragma unroll
    for (int si = 0; si < 2; ++si)
        #pragma unroll
        for (int sj = 0; sj < 2; ++sj) acc[si][sj] = (v4d){0., 0., 0., 0.};

    const int ra = tid >> 4;
    const int cs = (tid & 15) << 2;
    const double* gA = A + (size_t)(bm + ra) * DS + cs;
    const double* gB = B + (size_t)ra * DS + bn + cs;
    double va[4], vb[4];
    #pragma unroll
    for (int u = 0; u < 4; ++u) { va[u] = gA[u]; vb[u] = gB[u]; }

    for (int kt = 0; kt < DS; kt += 64) {
        #pragma unroll
        for (int u = 0; u < 4; ++u) {
            As[ra * PA + cs + u] = va[u];
            Bs[ra * PA + cs + u] = vb[u];
        }
        __syncthreads();
        if (kt + 64 < DS) {
            #pragma unroll
            for (int u = 0; u < 4; ++u) {
                va[u] = gA[kt + 64 + u];
                vb[u] = gB[(size_t)(kt + 64) * DS + u];
            }
        }
        #pragma unroll
        for (int s = 0; s < 4; ++s) {
            int k = (kg << 4) + (s << 2) + lk;
            double a0 = As[(wr + lr) * PA + k];
            double a1 = As[(wr + 16 + lr) * PA + k];
            double b0 = Bs[k * PA + wc + lr];
            double b1 = Bs[k * PA + wc + 16 + lr];
            acc[0][0] = __builtin_amdgcn_mfma_f64_16x16x4f64(a0, b0, acc[0][0], 0, 0, 0);
            acc[0][1] = __builtin_amdgcn_mfma_f64_16x16x4f64(a0, b1, acc[0][1], 0, 0, 0);
            acc[1][0] = __builtin_amdgcn_mfma_f64_16x16x4f64(a1, b0, acc[1][0], 0, 0, 0);
            acc[1][1] = __builtin_amdgcn_mfma_f64_16x16x4f64(a1, b1, acc[1][1], 0, 0, 0);
        }
        __syncthreads();
    }

    double* red = As;
    if (kg == 3) {
        #pragma unroll
        for (int si = 0; si < 2; ++si)
            #pragma unroll
            for (int sj = 0; sj < 2; ++sj)
                #pragma unroll
                for (int r = 0; r < 4; ++r)
                    red[(wr + si * 16 + lk + 4 * r) * 64 + wc + sj * 16 + lr]
                        = acc[si][sj][r];
    }
    __syncthreads();
    if (kg == 2) {
        #pragma unroll
        for (int si = 0; si < 2; ++si)
            #pragma unroll
            for (int sj = 0; sj < 2; ++sj)
                #pragma unroll
                for (int r = 0; r < 4; ++r)
                    red[(wr + si * 16 + lk + 4 * r) * 64 + wc + sj * 16 + lr]
                        += acc[si][sj][r];
    }
    __syncthreads();
    if (kg == 1) {
        #pragma unroll
        for (int si = 0; si < 2; ++si)
            #pragma unroll
            for (int sj = 0; sj < 2; ++sj)
                #pragma unroll
                for (int r = 0; r < 4; ++r)
                    red[(wr + si * 16 + lk + 4 * r) * 64 + wc + sj * 16 + lr]
                        += acc[si][sj][r];
    }
    __syncthreads();
    if (kg == 0) {
        #pragma unroll
        for (int si = 0; si < 2; ++si)
            #pragma unroll
            for (int sj = 0; sj < 2; ++sj) {
                int col = bn + wc + sj * 16 + lr;
                #pragma unroll
                for (int r = 0; r < 4; ++r) {
                    int row = bm + wr + si * 16 + lk + 4 * r;
                    D[(size_t)row * DS + col] = acc[si][sj][r]
                        + red[(wr + si * 16 + lk + 4 * r) * 64 + wc + sj * 16 + lr];
                }
            }
    }
}

// --------------------------------------------------------- init Y/Z ---------
__global__ __launch_bounds__(256)
void init_YZ(double* __restrict__ Y, double* __restrict__ Z)
{
    int idx = blockIdx.x * 256 + threadIdx.x;
    if (idx < 128 * 1024) {
        int r = idx >> 10, i = idx & 1023;
        double v = 0.0;
        if (r < 2 && i % 33 == 0) {
            int a = i / 33;
            if ((a < 16) == (r == 0)) v = 1.0;
        }
        Y[idx] = v;
    } else if (idx < 128 * 1024 + 1024) {
        int i = idx - 128 * 1024;
        Z[i] = (i == 528) ? 1.0 : 0.0;
    }
}

// --------------------------------------------------------- ypart ------------
// Partial of Yrows[0..32*gz) @ P over k-block by: scratch[(by*SR + r)*1024+c].
// Block (bx,by,bz): cols [64bx,+64), k [64by,+64), rows [32bz,+32).
// LDS-staged Y rows (broadcast reads), per-thread col, 4-wave reduce.
__global__ __launch_bounds__(256)
void ypart(const double* __restrict__ P, const double* __restrict__ Y,
           double* __restrict__ scratch, int SR)
{
    __shared__ double Yld[32 * 64];
    __shared__ double red[32 * 64];
    const int tid = threadIdx.x;
    const int cc = tid & 63, kw = tid >> 6;
    const int col = (blockIdx.x << 6) + cc;
    const int kb = blockIdx.y << 6;
    const int r0 = blockIdx.z << 5;

    for (int idx = tid; idx < 32 * 64; idx += 256) {
        int r = idx >> 6, kk = idx & 63;
        Yld[idx] = Y[(size_t)(r0 + r) * DS + kb + kk];
    }
    __syncthreads();

    double acc[32];
    #pragma unroll
    for (int r = 0; r < 32; ++r) acc[r] = 0.0;

    #pragma unroll
    for (int kk = 0; kk < 16; ++kk) {
        int kl = (kw << 4) + kk;
        double pv = P[(size_t)(kb + kl) * DS + col];
        #pragma unroll
        for (int r = 0; r < 32; ++r)
            acc[r] += Yld[(r << 6) + kl] * pv;    // same-addr broadcast
    }

    __syncthreads();
    if (kw == 3) {
        #pragma unroll
        for (int r = 0; r < 32; ++r) red[(r << 6) + cc] = acc[r];
    }
    __syncthreads();
    if (kw == 2) {
        #pragma unroll
        for (int r = 0; r < 32; ++r) red[(r << 6) + cc] += acc[r];
    }
    __syncthreads();
    if (kw == 1) {
        #pragma unroll
        for (int r = 0; r < 32; ++r) red[(r << 6) + cc] += acc[r];
    }
    __syncthreads();
    if (kw == 0) {
        #pragma unroll
        for (int r = 0; r < 32; ++r) red[(r << 6) + cc] += acc[r];
    }
    __syncthreads();
    for (int idx = tid; idx < 32 * 64; idx += 256) {
        int r = idx >> 6, c2 = idx & 63;
        scratch[((size_t)blockIdx.y * SR + r0 + r) * DS + (blockIdx.x << 6) + c2]
            = red[idx];
    }
}

// --------------------------------------------------------- yreduce ----------
// Y[M + r, c] = sum_q scratch[(q*SR + r)*1024 + c], r in [0, SR).
// Writes beyond 2M are zeros onto zeros (benign).
__global__ __launch_bounds__(256)
void yreduce(const double* __restrict__ scratch, double* __restrict__ Y,
             int M, int SR)
{
    int idx = blockIdx.x * 256 + threadIdx.x;
    int r = idx >> 10, c = idx & 1023;
    double s = 0.0;
    #pragma unroll
    for (int q = 0; q < 16; ++q)
        s += scratch[((size_t)q * SR + r) * DS + c];
    Y[(size_t)(M + r) * DS + c] = s;
}

// --------------------------------------------------------- Z matvec ---------
__global__ __launch_bounds__(256)
void zstep(const double* __restrict__ V, const double* __restrict__ Zin,
           double* __restrict__ Zout)
{
    int row = blockIdx.x * 4 + (threadIdx.x >> 6);
    int lane = threadIdx.x & 63;
    const double* r_ = V + (size_t)row * DS;
    double s = 0.0;
    for (int k = lane; k < DS; k += 64) s += r_[k] * Zin[k];
    #pragma unroll
    for (int off = 32; off; off >>= 1) s += __shfl_down(s, off);
    if (lane == 0) Zout[row] = s;
}

// --------------------------------------------------------- output -----------
// t = a + 64 j; y = Y row (2a+k); z = Z[j].
__global__ __launch_bounds__(128)
void final_pops(const double* __restrict__ Y, const double* __restrict__ Z,
                float* __restrict__ out, int n)
{
    int t = blockIdx.x;
    int k = threadIdx.x >> 6, lane = threadIdx.x & 63;
    int a = t & 63, j = t >> 6;
    const double* y = Y + (size_t)(2 * a + k) * 1024;
    const double* z = Z + (size_t)j * 1024;
    double s = 0.0;
    for (int i = lane; i < 1024; i += 64) s += y[i] * z[i];
    #pragma unroll
    for (int off = 32; off; off >>= 1) s += __shfl_down(s, off);
    if (lane == 0) {
        out[(size_t)(k + 1) * n + t] = (float)s;
        if (k == 0) out[t] = 0.0f;
    }
}

// --------------------------------------------------------- host -------------
static inline void ydouble2(const double* P, double* Y, double* scr, int M,
                            hipStream_t stream)
{
    int gz = (M == 64) ? 2 : 1;
    int SR = gz * 32;
    ypart<<<dim3(16, 16, gz), 256, 0, stream>>>(P, Y, scr, SR);
    yreduce<<<(SR * 1024) / 256, 256, 0, stream>>>(scr, Y, M, SR);
}

extern "C" void kernel_launch(void* const* d_in, const int* in_sizes, int n_in,
                              void* d_out, int out_size, void* d_ws, size_t ws_size,
                              hipStream_t stream)
{
    const float* logg = (const float*)d_in[0];
    float* out = (float*)d_out;
    const int n = out_size / 3;
    (void)in_sizes; (void)n_in; (void)ws_size;

    char* ws = (char*)d_ws;
    double* b0 = (double*)(ws + 0 * MATD);
    double* b1 = (double*)(ws + 1 * MATD);
    double* b2 = (double*)(ws + 2 * MATD);
    double* scr = (double*)(ws + 3 * MATD);  // 16 x 64 x 1024 partials (8 MB)
    double* Y  = (double*)(ws + 4 * MATD);   // 128 rows x 1024
    double* Z  = Y + 128 * 1024;             // 16 x 1024

    dim3 g2(16, 16);

    // ---- W = Taylor16(tau*T/8): G16 dense, then 15 sparse applies ----
    build_G16<<<4096, 256, 0, stream>>>(logg, b0);
    double* src = b0; double* dst = b1;
    for (int k = 15; k >= 1; --k) {
        apply_T<<<1024, 256, 0, stream>>>(logg, src, dst, 1.0 / (double)k);
        double* t = src; src = dst; dst = t;
    }
    // W in b1

    init_YZ<<<516, 256, 0, stream>>>(Y, Z);

    // ---- squarings interleaved with Y-doubling ----
    dgemm<<<g2, 1024, 0, stream>>>(b1, b1, b0);   // W^2
    dgemm<<<g2, 1024, 0, stream>>>(b0, b0, b2);   // W^4
    dgemm<<<g2, 1024, 0, stream>>>(b2, b2, b0);   // U = W^8
    ydouble2(b0, Y, scr, 2, stream);              // a += 1   (U)
    dgemm<<<g2, 1024, 0, stream>>>(b0, b0, b1);   // U^2
    ydouble2(b1, Y, scr, 4, stream);              // a += 2
    dgemm<<<g2, 1024, 0, stream>>>(b1, b1, b2);   // U^4
    ydouble2(b2, Y, scr, 8, stream);              // a += 4
    dgemm<<<g2, 1024, 0, stream>>>(b2, b2, b1);   // U^8
    ydouble2(b1, Y, scr, 16, stream);             // a += 8
    dgemm<<<g2, 1024, 0, stream>>>(b1, b1, b2);   // U^16
    ydouble2(b2, Y, scr, 32, stream);             // a += 16
    dgemm<<<g2, 1024, 0, stream>>>(b2, b2, b1);   // U^32
    ydouble2(b1, Y, scr, 64, stream);             // a += 32
    dgemm<<<g2, 1024, 0, stream>>>(b1, b1, b2);   // U^64

    // ---- Z chain: z_j = (U^64)^j x0, j = 1..15 ----
    for (int j = 1; j < 16; ++j)
        zstep<<<256, 256, 0, stream>>>(b2, Z + (size_t)(j - 1) * 1024,
                                       Z + (size_t)j * 1024);

    final_pops<<<n, 128, 0, stream>>>(Y, Z, out, n);
}